// Round 2
// baseline (126.296 us; speedup 1.0000x reference)
//
#include <hip/hip_runtime.h>
#include <hip/hip_bf16.h>

#define BDIM 256
#define NROW 64      // S = O = 64
#define DDIM 512
#define BK 128
#define NCHUNK 4     // 512/128
#define LDK 136      // BK + 8 bf16 pad (16B)
#define FDIM 32
#define BBATCH 32
#define NBLK (FDIM * BBATCH)

typedef short bf16x8 __attribute__((ext_vector_type(8)));
typedef float f32x4 __attribute__((ext_vector_type(4)));

__device__ __forceinline__ unsigned short f2bf(float f) {
    unsigned int u = __float_as_uint(f);
    u += 0x7FFFu + ((u >> 16) & 1u);   // round-to-nearest-even
    return (unsigned short)(u >> 16);
}

__global__ __launch_bounds__(BDIM, 4) void pwl_main(
        const float* __restrict__ pred, const float* __restrict__ slots,
        const int* __restrict__ labels, const unsigned char* __restrict__ vmask,
        float* __restrict__ gacc, int* __restrict__ gcnt,
        float* __restrict__ out) {
    // lA/lB staging; simbuf OVERLAYS lA (only used after last MFMA + barrier)
    __shared__ __align__(16) unsigned char smem[2 * NROW * LDK * sizeof(unsigned short)];
    unsigned short (*lA)[LDK] = reinterpret_cast<unsigned short(*)[LDK]>(smem);
    unsigned short (*lB)[LDK] = reinterpret_cast<unsigned short(*)[LDK]>(
        smem + NROW * LDK * sizeof(unsigned short));
    float (*simbuf)[65] = reinterpret_cast<float(*)[65]>(smem);  // 64*65*4=16640 <= 17408

    __shared__ float rnA[NROW], rnB[NROW];
    __shared__ float red_f;
    __shared__ int   red_i;
    __shared__ int   islast;
    __shared__ int   vsum;

    const int t   = threadIdx.x;
    const int bid = blockIdx.x;          // bid = b*F + f  (matches [B,F,...] layout)
    const int b   = bid >> 5;
    const int f   = bid & 31;
    const float* gA = slots + (size_t)bid * NROW * DDIM;
    const float* gB = pred  + (size_t)bid * NROW * DDIM;

    const int lane = t & 63;
    const int w    = t >> 6;
    const int wr   = (w >> 1) * 32;      // s-quadrant base
    const int wc   = (w & 1) * 32;       // o-quadrant base
    const int lr   = lane & 15;
    const int lk   = (lane >> 4) * 8;
    const int srow = t >> 5;             // staging sub-row (0..7)
    const int scol = t & 31;             // staging col group

    f32x4 acc00 = {0,0,0,0}, acc01 = {0,0,0,0}, acc10 = {0,0,0,0}, acc11 = {0,0,0,0};
    float sa[8], sb[8];
#pragma unroll
    for (int i = 0; i < 8; ++i) { sa[i] = 0.f; sb[i] = 0.f; }

    float4 ra[8], rb[8];
    // prologue: prefetch chunk 0
#pragma unroll
    for (int i = 0; i < 8; ++i) {
        const int row = i * 8 + srow;
        ra[i] = *reinterpret_cast<const float4*>(gA + row * DDIM + scol * 4);
        rb[i] = *reinterpret_cast<const float4*>(gB + row * DDIM + scol * 4);
    }

    for (int c = 0; c < NCHUNK; ++c) {
        if (c) __syncthreads();          // prev MFMA reads done before overwrite
        // convert + sumsq + LDS write (vmcnt wait happens here)
#pragma unroll
        for (int i = 0; i < 8; ++i) {
            const int row = i * 8 + srow;
            const float4 va = ra[i], vb = rb[i];
            sa[i] += va.x*va.x + va.y*va.y + va.z*va.z + va.w*va.w;
            sb[i] += vb.x*vb.x + vb.y*vb.y + vb.z*vb.z + vb.w*vb.w;
            ushort4 ua, ub;
            ua.x = f2bf(va.x); ua.y = f2bf(va.y); ua.z = f2bf(va.z); ua.w = f2bf(va.w);
            ub.x = f2bf(vb.x); ub.y = f2bf(vb.y); ub.z = f2bf(vb.z); ub.w = f2bf(vb.w);
            *reinterpret_cast<ushort4*>(&lA[row][scol * 4]) = ua;
            *reinterpret_cast<ushort4*>(&lB[row][scol * 4]) = ub;
        }
        // issue next chunk's loads — in flight across barrier + MFMA
        if (c + 1 < NCHUNK) {
            const int cb = (c + 1) * BK;
#pragma unroll
            for (int i = 0; i < 8; ++i) {
                const int row = i * 8 + srow;
                ra[i] = *reinterpret_cast<const float4*>(gA + row * DDIM + cb + scol * 4);
                rb[i] = *reinterpret_cast<const float4*>(gB + row * DDIM + cb + scol * 4);
            }
        }
        __syncthreads();
#pragma unroll
        for (int kk = 0; kk < 4; ++kk) {
            const int kb = kk * 32 + lk;
            const bf16x8 a0 = *reinterpret_cast<const bf16x8*>(&lA[wr      + lr][kb]);
            const bf16x8 a1 = *reinterpret_cast<const bf16x8*>(&lA[wr + 16 + lr][kb]);
            const bf16x8 b0 = *reinterpret_cast<const bf16x8*>(&lB[wc      + lr][kb]);
            const bf16x8 b1 = *reinterpret_cast<const bf16x8*>(&lB[wc + 16 + lr][kb]);
            acc00 = __builtin_amdgcn_mfma_f32_16x16x32_bf16(a0, b0, acc00, 0, 0, 0);
            acc01 = __builtin_amdgcn_mfma_f32_16x16x32_bf16(a0, b1, acc01, 0, 0, 0);
            acc10 = __builtin_amdgcn_mfma_f32_16x16x32_bf16(a1, b0, acc10, 0, 0, 0);
            acc11 = __builtin_amdgcn_mfma_f32_16x16x32_bf16(a1, b1, acc11, 0, 0, 0);
        }
    }

    // row sum-of-squares -> reciprocal norms (reduce across 32-lane halves)
#pragma unroll
    for (int i = 0; i < 8; ++i) {
        float x = sa[i], y = sb[i];
#pragma unroll
        for (int m = 1; m <= 16; m <<= 1) { x += __shfl_xor(x, m); y += __shfl_xor(y, m); }
        if ((t & 31) == 0) {
            const int row = i * 8 + srow;
            rnA[row] = 1.f / fmaxf(sqrtf(x), 1e-12f);
            rnB[row] = 1.f / fmaxf(sqrtf(y), 1e-12f);
        }
    }
    if (t == 0) { red_f = 0.f; red_i = 0; }
    __syncthreads();   // all MFMA done -> simbuf (overlaying lA) safe to write

    // normalize accumulators, write sim to LDS (C/D layout: col=lane&15, row=(lane>>4)*4+j)
    {
        const int r0 = wr + (lane >> 4) * 4;
        const int c0 = wc + lr;
#pragma unroll
        for (int j = 0; j < 4; ++j) {
            simbuf[r0 + j     ][c0     ] = acc00[j] * rnA[r0 + j     ] * rnB[c0     ];
            simbuf[r0 + j     ][c0 + 16] = acc01[j] * rnA[r0 + j     ] * rnB[c0 + 16];
            simbuf[r0 + 16 + j][c0     ] = acc10[j] * rnA[r0 + 16 + j] * rnB[c0     ];
            simbuf[r0 + 16 + j][c0 + 16] = acc11[j] * rnA[r0 + 16 + j] * rnB[c0 + 16];
        }
    }
    __syncthreads();

    // softmax over objects + focal at label; 4 lanes per s-row
    {
        const int s = t >> 2;
        const int q = t & 3;
        float v[16];
        float mx = -1e30f;
#pragma unroll
        for (int jj = 0; jj < 16; ++jj) {
            v[jj] = simbuf[s][q * 16 + jj];
            mx = fmaxf(mx, v[jj]);
        }
        mx = fmaxf(mx, __shfl_xor(mx, 1));
        mx = fmaxf(mx, __shfl_xor(mx, 2));
        float se = 0.f;
#pragma unroll
        for (int jj = 0; jj < 16; ++jj) se += __expf(v[jj] - mx);
        se += __shfl_xor(se, 1);
        se += __shfl_xor(se, 2);
        if (q == 0) {
            const int lab = labels[(f * BBATCH + b) * NROW + s];
            if (lab >= 0) {
                const float simt  = simbuf[s][lab];
                const float pt    = __expf(simt - mx) / se;
                const float u     = 1.f - pt + 1e-12f;
                const float focal = u * u * __logf(pt + 1e-12f);
                atomicAdd(&red_f, focal);
                atomicAdd(&red_i, 1);
            }
        }
    }
    __syncthreads();
    if (t == 0) {
        const float cnt = fmaxf((float)red_i, 1.f);
        const float nll = -red_f / cnt;
        const float vv  = vmask[f * BBATCH + b] ? 1.f : 0.f;
        atomicAdd(gacc, 100.f * nll * vv);
        __threadfence();                        // release: loss add visible before count
        const int old = atomicAdd(gcnt, 1);
        islast = (old == NBLK - 1) ? 1 : 0;
        vsum = 0;
    }
    __syncthreads();

    // last block folds the finalize: sum(vmask) + final division
    if (islast) {
        int loc = 0;
        for (int i = t; i < NBLK; i += BDIM) loc += (vmask[i] != 0) ? 1 : 0;
#pragma unroll
        for (int m = 1; m <= 32; m <<= 1) loc += __shfl_xor(loc, m);
        if (lane == 0) atomicAdd(&vsum, loc);
        __syncthreads();
        if (t == 0) {
            __threadfence();                    // acquire side
            const float loss = atomicAdd(gacc, 0.f);   // device-scope coherent read
            const float sums = (float)vsum;
            out[0] = (sums > 0.f) ? loss / (32.0f * sums) : loss;
        }
    }
}

extern "C" void kernel_launch(void* const* d_in, const int* in_sizes, int n_in,
                              void* d_out, int out_size, void* d_ws, size_t ws_size,
                              hipStream_t stream) {
    const float* pred          = (const float*)d_in[0];
    const float* slots         = (const float*)d_in[1];
    const int* labels          = (const int*)d_in[2];
    const unsigned char* vmask = (const unsigned char*)d_in[3];
    float* out  = (float*)d_out;
    float* gacc = (float*)d_ws;
    int*   gcnt = (int*)((char*)d_ws + sizeof(float));

    hipMemsetAsync(d_ws, 0, 8, stream);
    pwl_main<<<dim3(NBLK), dim3(BDIM), 0, stream>>>(pred, slots, labels, vmask, gacc, gcnt, out);
}

// Round 3
// 81.356 us; speedup vs baseline: 1.5524x; 1.5524x over previous
//
#include <hip/hip_runtime.h>
#include <hip/hip_bf16.h>

#define BDIM 256
#define NROW 64      // S = O = 64
#define DDIM 512
#define BK 128
#define NCHUNK 4     // 512/128
#define LDK 136      // BK + 8 bf16 pad (16B)
#define FDIM 32
#define BBATCH 32
#define NBLK (FDIM * BBATCH)

typedef short bf16x8 __attribute__((ext_vector_type(8)));
typedef float f32x4 __attribute__((ext_vector_type(4)));

__device__ __forceinline__ unsigned short f2bf(float f) {
    unsigned int u = __float_as_uint(f);
    u += 0x7FFFu + ((u >> 16) & 1u);   // round-to-nearest-even
    return (unsigned short)(u >> 16);
}

__global__ __launch_bounds__(BDIM, 4) void pwl_main(
        const float* __restrict__ pred, const float* __restrict__ slots,
        const int* __restrict__ labels, const unsigned char* __restrict__ vmask,
        float* __restrict__ gacc, int* __restrict__ gcnt,
        float* __restrict__ out) {
    // lA/lB staging; simbuf OVERLAYS lA (only used after last MFMA + barrier)
    __shared__ __align__(16) unsigned char smem[2 * NROW * LDK * sizeof(unsigned short)];
    unsigned short (*lA)[LDK] = reinterpret_cast<unsigned short(*)[LDK]>(smem);
    unsigned short (*lB)[LDK] = reinterpret_cast<unsigned short(*)[LDK]>(
        smem + NROW * LDK * sizeof(unsigned short));
    float (*simbuf)[65] = reinterpret_cast<float(*)[65]>(smem);  // 64*65*4=16640 <= 17408

    __shared__ float rnA[NROW], rnB[NROW];
    __shared__ float red_f;
    __shared__ int   red_i;
    __shared__ int   islast;
    __shared__ int   vsum;

    const int t   = threadIdx.x;
    const int bid = blockIdx.x;          // bid = b*F + f  (matches [B,F,...] layout)
    const int b   = bid >> 5;
    const int f   = bid & 31;
    const float* gA = slots + (size_t)bid * NROW * DDIM;
    const float* gB = pred  + (size_t)bid * NROW * DDIM;

    const int lane = t & 63;
    const int w    = t >> 6;
    const int wr   = (w >> 1) * 32;      // s-quadrant base
    const int wc   = (w & 1) * 32;       // o-quadrant base
    const int lr   = lane & 15;
    const int lk   = (lane >> 4) * 8;
    const int srow = t >> 5;             // staging sub-row (0..7)
    const int scol = t & 31;             // staging col group

    f32x4 acc00 = {0,0,0,0}, acc01 = {0,0,0,0}, acc10 = {0,0,0,0}, acc11 = {0,0,0,0};
    float sa[8], sb[8];
#pragma unroll
    for (int i = 0; i < 8; ++i) { sa[i] = 0.f; sb[i] = 0.f; }

    for (int c = 0; c < NCHUNK; ++c) {
        if (c) __syncthreads();          // prev MFMA reads done before overwrite
        const int cbase = c * BK;
        // load + sumsq + convert + LDS write (loads consumed in-place: no spill)
#pragma unroll
        for (int i = 0; i < 8; ++i) {
            const int row = i * 8 + srow;
            const float4 va = *reinterpret_cast<const float4*>(gA + row * DDIM + cbase + scol * 4);
            const float4 vb = *reinterpret_cast<const float4*>(gB + row * DDIM + cbase + scol * 4);
            sa[i] += va.x*va.x + va.y*va.y + va.z*va.z + va.w*va.w;
            sb[i] += vb.x*vb.x + vb.y*vb.y + vb.z*vb.z + vb.w*vb.w;
            ushort4 ua, ub;
            ua.x = f2bf(va.x); ua.y = f2bf(va.y); ua.z = f2bf(va.z); ua.w = f2bf(va.w);
            ub.x = f2bf(vb.x); ub.y = f2bf(vb.y); ub.z = f2bf(vb.z); ub.w = f2bf(vb.w);
            *reinterpret_cast<ushort4*>(&lA[row][scol * 4]) = ua;
            *reinterpret_cast<ushort4*>(&lB[row][scol * 4]) = ub;
        }
        __syncthreads();
#pragma unroll
        for (int kk = 0; kk < 4; ++kk) {
            const int kb = kk * 32 + lk;
            const bf16x8 a0 = *reinterpret_cast<const bf16x8*>(&lA[wr      + lr][kb]);
            const bf16x8 a1 = *reinterpret_cast<const bf16x8*>(&lA[wr + 16 + lr][kb]);
            const bf16x8 b0 = *reinterpret_cast<const bf16x8*>(&lB[wc      + lr][kb]);
            const bf16x8 b1 = *reinterpret_cast<const bf16x8*>(&lB[wc + 16 + lr][kb]);
            acc00 = __builtin_amdgcn_mfma_f32_16x16x32_bf16(a0, b0, acc00, 0, 0, 0);
            acc01 = __builtin_amdgcn_mfma_f32_16x16x32_bf16(a0, b1, acc01, 0, 0, 0);
            acc10 = __builtin_amdgcn_mfma_f32_16x16x32_bf16(a1, b0, acc10, 0, 0, 0);
            acc11 = __builtin_amdgcn_mfma_f32_16x16x32_bf16(a1, b1, acc11, 0, 0, 0);
        }
    }

    // row sum-of-squares -> reciprocal norms (reduce across 32-lane halves)
#pragma unroll
    for (int i = 0; i < 8; ++i) {
        float x = sa[i], y = sb[i];
#pragma unroll
        for (int m = 1; m <= 16; m <<= 1) { x += __shfl_xor(x, m); y += __shfl_xor(y, m); }
        if ((t & 31) == 0) {
            const int row = i * 8 + srow;
            rnA[row] = 1.f / fmaxf(sqrtf(x), 1e-12f);
            rnB[row] = 1.f / fmaxf(sqrtf(y), 1e-12f);
        }
    }
    if (t == 0) { red_f = 0.f; red_i = 0; }
    __syncthreads();   // all MFMA done -> simbuf (overlaying lA) safe to write

    // normalize accumulators, write sim to LDS (C/D layout: col=lane&15, row=(lane>>4)*4+j)
    {
        const int r0 = wr + (lane >> 4) * 4;
        const int c0 = wc + lr;
#pragma unroll
        for (int j = 0; j < 4; ++j) {
            simbuf[r0 + j     ][c0     ] = acc00[j] * rnA[r0 + j     ] * rnB[c0     ];
            simbuf[r0 + j     ][c0 + 16] = acc01[j] * rnA[r0 + j     ] * rnB[c0 + 16];
            simbuf[r0 + 16 + j][c0     ] = acc10[j] * rnA[r0 + 16 + j] * rnB[c0     ];
            simbuf[r0 + 16 + j][c0 + 16] = acc11[j] * rnA[r0 + 16 + j] * rnB[c0 + 16];
        }
    }
    __syncthreads();

    // softmax over objects + focal at label; 4 lanes per s-row
    {
        const int s = t >> 2;
        const int q = t & 3;
        float v[16];
        float mx = -1e30f;
#pragma unroll
        for (int jj = 0; jj < 16; ++jj) {
            v[jj] = simbuf[s][q * 16 + jj];
            mx = fmaxf(mx, v[jj]);
        }
        mx = fmaxf(mx, __shfl_xor(mx, 1));
        mx = fmaxf(mx, __shfl_xor(mx, 2));
        float se = 0.f;
#pragma unroll
        for (int jj = 0; jj < 16; ++jj) se += __expf(v[jj] - mx);
        se += __shfl_xor(se, 1);
        se += __shfl_xor(se, 2);
        if (q == 0) {
            const int lab = labels[(f * BBATCH + b) * NROW + s];
            if (lab >= 0) {
                const float simt  = simbuf[s][lab];
                const float pt    = __expf(simt - mx) / se;
                const float u     = 1.f - pt + 1e-12f;
                const float focal = u * u * __logf(pt + 1e-12f);
                atomicAdd(&red_f, focal);
                atomicAdd(&red_i, 1);
            }
        }
    }
    __syncthreads();
    if (t == 0) {
        const float cnt = fmaxf((float)red_i, 1.f);
        const float nll = -red_f / cnt;
        const float vv  = vmask[f * BBATCH + b] ? 1.f : 0.f;
        atomicAdd(gacc, 100.f * nll * vv);
        __threadfence();                        // release: loss add visible before count
        const int old = atomicAdd(gcnt, 1);
        islast = (old == NBLK - 1) ? 1 : 0;
        vsum = 0;
    }
    __syncthreads();

    // last block folds the finalize: sum(vmask) + final division
    if (islast) {
        int loc = 0;
        for (int i = t; i < NBLK; i += BDIM) loc += (vmask[i] != 0) ? 1 : 0;
#pragma unroll
        for (int m = 1; m <= 32; m <<= 1) loc += __shfl_xor(loc, m);
        if (lane == 0) atomicAdd(&vsum, loc);
        __syncthreads();
        if (t == 0) {
            __threadfence();                    // acquire side
            const float loss = atomicAdd(gacc, 0.f);   // device-scope coherent read
            const float sums = (float)vsum;
            out[0] = (sums > 0.f) ? loss / (32.0f * sums) : loss;
        }
    }
}

extern "C" void kernel_launch(void* const* d_in, const int* in_sizes, int n_in,
                              void* d_out, int out_size, void* d_ws, size_t ws_size,
                              hipStream_t stream) {
    const float* pred          = (const float*)d_in[0];
    const float* slots         = (const float*)d_in[1];
    const int* labels          = (const int*)d_in[2];
    const unsigned char* vmask = (const unsigned char*)d_in[3];
    float* out  = (float*)d_out;
    float* gacc = (float*)d_ws;
    int*   gcnt = (int*)((char*)d_ws + sizeof(float));

    hipMemsetAsync(d_ws, 0, 8, stream);
    pwl_main<<<dim3(NBLK), dim3(BDIM), 0, stream>>>(pred, slots, labels, vmask, gacc, gcnt, out);
}

// Round 4
// 49.448 us; speedup vs baseline: 2.5541x; 1.6453x over previous
//
#include <hip/hip_runtime.h>
#include <hip/hip_bf16.h>

#define BDIM 256
#define NROW 64      // S = O = 64
#define DDIM 512
#define BK 128
#define NCHUNK 4     // 512/128
#define LDK 136      // BK + 8 bf16 pad (16B)
#define FDIM 32
#define BBATCH 32
#define NBLK (FDIM * BBATCH)

typedef short bf16x8 __attribute__((ext_vector_type(8)));
typedef float f32x4 __attribute__((ext_vector_type(4)));

__device__ __forceinline__ unsigned short f2bf(float f) {
    unsigned int u = __float_as_uint(f);
    u += 0x7FFFu + ((u >> 16) & 1u);   // round-to-nearest-even
    return (unsigned short)(u >> 16);
}

__global__ __launch_bounds__(BDIM, 4) void pwl_main(
        const float* __restrict__ pred, const float* __restrict__ slots,
        const int* __restrict__ labels, const unsigned char* __restrict__ vmask,
        float* __restrict__ partial) {
    // lA/lB staging; simbuf OVERLAYS lA (only used after last MFMA + barrier)
    __shared__ __align__(16) unsigned char smem[2 * NROW * LDK * sizeof(unsigned short)];
    unsigned short (*lA)[LDK] = reinterpret_cast<unsigned short(*)[LDK]>(smem);
    unsigned short (*lB)[LDK] = reinterpret_cast<unsigned short(*)[LDK]>(
        smem + NROW * LDK * sizeof(unsigned short));
    float (*simbuf)[65] = reinterpret_cast<float(*)[65]>(smem);  // 64*65*4=16640 <= 17408

    __shared__ float rnA[NROW], rnB[NROW];
    __shared__ float wsum_f[4], wsum_c[4];

    const int t   = threadIdx.x;
    const int bid = blockIdx.x;          // bid = b*F + f  (matches [B,F,...] layout)
    const int b   = bid >> 5;
    const int f   = bid & 31;
    const float* gA = slots + (size_t)bid * NROW * DDIM;
    const float* gB = pred  + (size_t)bid * NROW * DDIM;

    const int lane = t & 63;
    const int w    = t >> 6;
    const int wr   = (w >> 1) * 32;      // s-quadrant base
    const int wc   = (w & 1) * 32;       // o-quadrant base
    const int lr   = lane & 15;
    const int lk   = (lane >> 4) * 8;
    const int srow = t >> 5;             // staging sub-row (0..7)
    const int scol = t & 31;             // staging col group

    f32x4 acc00 = {0,0,0,0}, acc01 = {0,0,0,0}, acc10 = {0,0,0,0}, acc11 = {0,0,0,0};
    float sa[8], sb[8];
#pragma unroll
    for (int i = 0; i < 8; ++i) { sa[i] = 0.f; sb[i] = 0.f; }

    for (int c = 0; c < NCHUNK; ++c) {
        if (c) __syncthreads();          // prev MFMA reads done before overwrite
        const int cbase = c * BK;
        // load + sumsq + convert + LDS write (loads consumed in-place: no spill)
#pragma unroll
        for (int i = 0; i < 8; ++i) {
            const int row = i * 8 + srow;
            const float4 va = *reinterpret_cast<const float4*>(gA + row * DDIM + cbase + scol * 4);
            const float4 vb = *reinterpret_cast<const float4*>(gB + row * DDIM + cbase + scol * 4);
            sa[i] += va.x*va.x + va.y*va.y + va.z*va.z + va.w*va.w;
            sb[i] += vb.x*vb.x + vb.y*vb.y + vb.z*vb.z + vb.w*vb.w;
            ushort4 ua, ub;
            ua.x = f2bf(va.x); ua.y = f2bf(va.y); ua.z = f2bf(va.z); ua.w = f2bf(va.w);
            ub.x = f2bf(vb.x); ub.y = f2bf(vb.y); ub.z = f2bf(vb.z); ub.w = f2bf(vb.w);
            *reinterpret_cast<ushort4*>(&lA[row][scol * 4]) = ua;
            *reinterpret_cast<ushort4*>(&lB[row][scol * 4]) = ub;
        }
        __syncthreads();
#pragma unroll
        for (int kk = 0; kk < 4; ++kk) {
            const int kb = kk * 32 + lk;
            const bf16x8 a0 = *reinterpret_cast<const bf16x8*>(&lA[wr      + lr][kb]);
            const bf16x8 a1 = *reinterpret_cast<const bf16x8*>(&lA[wr + 16 + lr][kb]);
            const bf16x8 b0 = *reinterpret_cast<const bf16x8*>(&lB[wc      + lr][kb]);
            const bf16x8 b1 = *reinterpret_cast<const bf16x8*>(&lB[wc + 16 + lr][kb]);
            acc00 = __builtin_amdgcn_mfma_f32_16x16x32_bf16(a0, b0, acc00, 0, 0, 0);
            acc01 = __builtin_amdgcn_mfma_f32_16x16x32_bf16(a0, b1, acc01, 0, 0, 0);
            acc10 = __builtin_amdgcn_mfma_f32_16x16x32_bf16(a1, b0, acc10, 0, 0, 0);
            acc11 = __builtin_amdgcn_mfma_f32_16x16x32_bf16(a1, b1, acc11, 0, 0, 0);
        }
    }

    // row sum-of-squares -> reciprocal norms (reduce across 32-lane halves)
#pragma unroll
    for (int i = 0; i < 8; ++i) {
        float x = sa[i], y = sb[i];
#pragma unroll
        for (int m = 1; m <= 16; m <<= 1) { x += __shfl_xor(x, m); y += __shfl_xor(y, m); }
        if ((t & 31) == 0) {
            const int row = i * 8 + srow;
            rnA[row] = 1.f / fmaxf(sqrtf(x), 1e-12f);
            rnB[row] = 1.f / fmaxf(sqrtf(y), 1e-12f);
        }
    }
    __syncthreads();   // all MFMA done -> simbuf (overlaying lA) safe to write

    // normalize accumulators, write sim to LDS (C/D layout: col=lane&15, row=(lane>>4)*4+j)
    {
        const int r0 = wr + (lane >> 4) * 4;
        const int c0 = wc + lr;
#pragma unroll
        for (int j = 0; j < 4; ++j) {
            simbuf[r0 + j     ][c0     ] = acc00[j] * rnA[r0 + j     ] * rnB[c0     ];
            simbuf[r0 + j     ][c0 + 16] = acc01[j] * rnA[r0 + j     ] * rnB[c0 + 16];
            simbuf[r0 + 16 + j][c0     ] = acc10[j] * rnA[r0 + 16 + j] * rnB[c0     ];
            simbuf[r0 + 16 + j][c0 + 16] = acc11[j] * rnA[r0 + 16 + j] * rnB[c0 + 16];
        }
    }
    __syncthreads();

    // softmax over objects + focal at label; 4 lanes per s-row
    float contrib = 0.f, ccnt = 0.f;
    {
        const int s = t >> 2;
        const int q = t & 3;
        float v[16];
        float mx = -1e30f;
#pragma unroll
        for (int jj = 0; jj < 16; ++jj) {
            v[jj] = simbuf[s][q * 16 + jj];
            mx = fmaxf(mx, v[jj]);
        }
        mx = fmaxf(mx, __shfl_xor(mx, 1));
        mx = fmaxf(mx, __shfl_xor(mx, 2));
        float se = 0.f;
#pragma unroll
        for (int jj = 0; jj < 16; ++jj) se += __expf(v[jj] - mx);
        se += __shfl_xor(se, 1);
        se += __shfl_xor(se, 2);
        if (q == 0) {
            const int lab = labels[(f * BBATCH + b) * NROW + s];
            if (lab >= 0) {
                const float simt  = simbuf[s][lab];
                const float pt    = __expf(simt - mx) / se;
                const float u     = 1.f - pt + 1e-12f;
                const float focal = u * u * __logf(pt + 1e-12f);
                contrib = focal;
                ccnt    = 1.f;
            }
        }
    }
    // wave-level reduce (no LDS/global atomics anywhere)
#pragma unroll
    for (int m = 1; m <= 32; m <<= 1) {
        contrib += __shfl_xor(contrib, m);
        ccnt    += __shfl_xor(ccnt, m);
    }
    if (lane == 0) { wsum_f[w] = contrib; wsum_c[w] = ccnt; }
    __syncthreads();
    if (t == 0) {
        const float rf  = wsum_f[0] + wsum_f[1] + wsum_f[2] + wsum_f[3];
        const float ri  = wsum_c[0] + wsum_c[1] + wsum_c[2] + wsum_c[3];
        const float cnt = fmaxf(ri, 1.f);
        const float nll = -rf / cnt;
        const float vv  = vmask[f * BBATCH + b] ? 1.f : 0.f;
        partial[bid] = 100.f * nll * vv;   // distinct address per block: no contention
    }
}

__global__ __launch_bounds__(BDIM) void pwl_finalize(
        const unsigned char* __restrict__ vmask, const float* __restrict__ partial,
        float* __restrict__ out) {
    __shared__ float sf[4], sv[4];
    const int t = threadIdx.x;
    const float4 p = reinterpret_cast<const float4*>(partial)[t];      // 256*4 = 1024
    float s = p.x + p.y + p.z + p.w;
    const uchar4 mv = reinterpret_cast<const uchar4*>(vmask)[t];       // 256*4 = 1024
    float vs = (mv.x ? 1.f : 0.f) + (mv.y ? 1.f : 0.f) + (mv.z ? 1.f : 0.f) + (mv.w ? 1.f : 0.f);
#pragma unroll
    for (int m = 1; m <= 32; m <<= 1) { s += __shfl_xor(s, m); vs += __shfl_xor(vs, m); }
    if ((t & 63) == 0) { sf[t >> 6] = s; sv[t >> 6] = vs; }
    __syncthreads();
    if (t == 0) {
        const float loss = sf[0] + sf[1] + sf[2] + sf[3];
        const float sums = sv[0] + sv[1] + sv[2] + sv[3];
        out[0] = (sums > 0.f) ? loss / (32.0f * sums) : loss;
    }
}

extern "C" void kernel_launch(void* const* d_in, const int* in_sizes, int n_in,
                              void* d_out, int out_size, void* d_ws, size_t ws_size,
                              hipStream_t stream) {
    const float* pred          = (const float*)d_in[0];
    const float* slots         = (const float*)d_in[1];
    const int* labels          = (const int*)d_in[2];
    const unsigned char* vmask = (const unsigned char*)d_in[3];
    float* out     = (float*)d_out;
    float* partial = (float*)d_ws;   // 1024 floats; every slot written every call

    pwl_main<<<dim3(NBLK), dim3(BDIM), 0, stream>>>(pred, slots, labels, vmask, partial);
    pwl_finalize<<<dim3(1), dim3(BDIM), 0, stream>>>(vmask, partial, out);
}